// Round 5
// baseline (131.166 us; speedup 1.0000x reference)
//
#include <hip/hip_runtime.h>

// SimpleMatcher: B=128, N=900 preds, T=300 targets.
// out = [pred_idx (B*T), valid (B*T), max_iou (B*T)] as float.
//
// R10: three scan-structure theories in a row (LDS throughput R8, scalar
// pipe R6/7, register starvation R9) each predicted -15us and delivered
// ~0. Conclusion: the by-subtraction scan estimate (~33us) is not
// trustworthy, and no kernel of ours has appeared in top-5 counters since
// R6 (poison fills saturate the window). R10 restructures for BOTH perf
// and visibility: FUSE finish into scan (2 dispatches -> 1). Per (b,tc)
// the NSPLIT=5 sibling blocks have consecutive blockIdx (near-zero
// dispatch skew); each publishes results, __threadfence() (device scope,
// needed across per-XCD L2s), then atomicExch-es a flag to MAGIC
// 0x13579BDF (distinct bytes: byte-fill ws-poison can never equal it).
// The ns==0 sibling spins on the 4 flags (384 max spinners << 1024
// resident blocks -> no deadlock), acquires, and runs the combine +
// MARGIN path + ambiguous rescan inline for its 128 (or 44) targets.
// Removes: finish dispatch, its launch gap, cold re-read of 2.3MB.
// Scan phase itself is R9's (dual-target, 1 ds_read_b128/iter, 64-VGPR).
// Numerics unchanged (R5..R9 all passed, absmax 1.0).
// Fixed floor: harness 256MiB ws-poison fill (~40us) in-window.

#define BB 128
#define NN 900
#define TT 300
#define NSPLIT 5       // n-splits across blocks
#define NPB 180        // preds per block  (NN / NSPLIT)
#define NPW 45         // preds per wave   (NPB / 4)
#define MARGIN 2e-5f
#define MAGIC 0x13579BDF  // distinct bytes => no byte-fill poison collision

// Bit-exact GIoU in numpy's exact expression order.
__device__ __forceinline__ float giou_exact(float4 pb, float4 tb) {
#pragma clang fp contract(off)
    float px0 = pb.x - 0.5f * pb.z, py0 = pb.y - 0.5f * pb.w;
    float px1 = pb.x + 0.5f * pb.z, py1 = pb.y + 0.5f * pb.w;
    float tx0 = tb.x - 0.5f * tb.z, ty0 = tb.y - 0.5f * tb.w;
    float tx1 = tb.x + 0.5f * tb.z, ty1 = tb.y + 0.5f * tb.w;
    float pa = (px1 - px0) * (py1 - py0);
    float ta = (tx1 - tx0) * (ty1 - ty0);
    float w  = fmaxf(fminf(px1, tx1) - fmaxf(px0, tx0), 0.f);
    float h  = fmaxf(fminf(py1, ty1) - fmaxf(py0, ty0), 0.f);
    float inter = w * h;
    float uni   = pa + ta - inter;
    float iou   = inter / uni;            // correctly-rounded IEEE div
    float ew = fmaxf(fmaxf(px1, tx1) - fminf(px0, tx0), 0.f);
    float eh = fmaxf(fmaxf(py1, ty1) - fminf(py0, ty0), 0.f);
    float ea = ew * eh;
    return iou - (ea - uni) / ea;         // correctly-rounded IEEE div
}

// One GIoU step vs the LDS-broadcast pred (q + derived pa,pw,ph), top-2.
__device__ __forceinline__ void giou_step(
    const float4 q, const float pa, const float pw, const float ph,
    const float tx0, const float ty0, const float tx1, const float ty1,
    const float tw, const float th, const float ta, const int k,
    float& best, float& second, int& bidxl)
{
    const float m1x = fminf(q.z, tx1);
    const float M0x = fmaxf(q.x, tx0);
    const float wr  = m1x - M0x;          // unclamped intersect width
    const float w   = fmaxf(wr, 0.f);
    const float m1y = fminf(q.w, ty1);
    const float M0y = fmaxf(q.y, ty0);
    const float hr  = m1y - M0y;
    const float h   = fmaxf(hr, 0.f);
    const float inter = w * h;
    const float uni   = (pa + ta) - inter;
    // min+max=sum identity: ew = max(px1,tx1)-min(px0,tx0) = pw+tw-wr
    const float ew = (pw + tw) - wr;
    const float eh = (ph + th) - hr;
    const float ea = ew * eh;
    // g = inter/uni - (ea-uni)/ea == (inter*ea + uni*(uni-ea))/(uni*ea)
    const float num = fmaf(inter, ea, uni * (uni - ea));
    const float g   = num * __builtin_amdgcn_rcpf(uni * ea);
    second = __builtin_amdgcn_fmed3f(g, best, second);  // new 2nd-max
    if (g > best) bidxl = k;
    best = fmaxf(best, g);
}

__device__ __forceinline__ void load_target(
    const float4* __restrict__ tgt, const int idx,
    float& tx0, float& ty0, float& tx1, float& ty1,
    float& tw, float& th, float& ta)
{
    const float4 tb = tgt[idx];
    tx0 = tb.x - 0.5f * tb.z;
    ty0 = tb.y - 0.5f * tb.w;
    tx1 = tb.x + 0.5f * tb.z;
    ty1 = tb.y + 0.5f * tb.w;
    tw = tx1 - tx0;
    th = ty1 - ty0;
    ta = tw * th;                         // == reference area_t
}

// Grid: BB * 3 * NSPLIT. tc=0,1: dual blocks (targets tc*128 .. +127,
// lane owns t and t+64). tc=2: single block (targets 256..299).
// ns==0 block of each (b,tc) additionally runs the finish phase after
// its 4 siblings raise their flags.
__global__ __launch_bounds__(256, 4) void matcher_fused_kernel(
    const float4* __restrict__ pred,      // [B*N] cxcywh
    const float4* __restrict__ tgt,       // [B*T] cxcywh
    const unsigned char* __restrict__ mask,
    float* __restrict__ pbest,            // [NSPLIT][B*T]
    float* __restrict__ psec,             // [NSPLIT][B*T]
    int*   __restrict__ pidx,             // [NSPLIT][B*T]
    int*   __restrict__ flags,            // [BB*3*NSPLIT]
    float* __restrict__ out)
{
    __shared__ float4 sq[NPB];            // pred xyxy (only LDS pred data)
    __shared__ float rb1[256], rs1[256], rb2[256], rs2[256];
    __shared__ int   ri1[256], ri2[256];
    __shared__ int   sflag[128];
    __shared__ int   scount;

    const int ns  = blockIdx.x % NSPLIT;
    const int tc  = (blockIdx.x / NSPLIT) % 3;
    const int b   = blockIdx.x / (NSPLIT * 3);
    const int tid = threadIdx.x;
    const int tl  = tid & 63;
    const int ng  = tid >> 6;

    if (tid == 0) scount = 0;
    if (tid < NPB) {
        const float4 pb = pred[b * NN + ns * NPB + tid];
        float4 q;
        q.x = pb.x - 0.5f * pb.z;
        q.y = pb.y - 0.5f * pb.w;
        q.z = pb.x + 0.5f * pb.z;
        q.w = pb.y + 0.5f * pb.w;
        sq[tid] = q;
    }
    __syncthreads();

    const int k0 = ng * NPW;

    if (tc < 2) {
        // ---- dual path: both targets always valid (max index 255) ----
        const int t1 = tc * 128 + tl;
        const int t2 = t1 + 64;
        float ax0, ay0, ax1, ay1, aw, ah, aa;
        float bx0, by0, bx1, by1, bw, bh, ba;
        load_target(tgt, b * TT + t1, ax0, ay0, ax1, ay1, aw, ah, aa);
        load_target(tgt, b * TT + t2, bx0, by0, bx1, by1, bw, bh, ba);

        float best1 = -INFINITY, sec1 = -INFINITY;
        float best2 = -INFINITY, sec2 = -INFINITY;
        int   i1 = 0, i2 = 0;
        #pragma unroll 3
        for (int k = 0; k < NPW; ++k) {
            const float4 q = sq[k0 + k];  // wave-uniform -> LDS broadcast
            const float pw = q.z - q.x;   // derived, bit-identical to R8
            const float ph = q.w - q.y;
            const float pa = pw * ph;
            giou_step(q, pa, pw, ph, ax0, ay0, ax1, ay1, aw, ah, aa, k,
                      best1, sec1, i1);
            giou_step(q, pa, pw, ph, bx0, by0, bx1, by1, bw, bh, ba, k,
                      best2, sec2, i2);
        }
        int bi1 = k0 + i1, bi2 = k0 + i2;

        rb1[tid] = best1; rs1[tid] = sec1; ri1[tid] = bi1;
        rb2[tid] = best2; rs2[tid] = sec2; ri2[tid] = bi2;
        __syncthreads();

        if (ng == 0) {
            for (int s = 1; s < 4; ++s) { // ascending wave = ascending n
                const float ob1 = rb1[s * 64 + tl];
                const float os1 = rs1[s * 64 + tl];
                const int   oi1 = ri1[s * 64 + tl];
                sec1 = fmaxf(fminf(best1, ob1), fmaxf(sec1, os1));
                if (ob1 > best1) { best1 = ob1; bi1 = oi1; }
                const float ob2 = rb2[s * 64 + tl];
                const float os2 = rs2[s * 64 + tl];
                const int   oi2 = ri2[s * 64 + tl];
                sec2 = fmaxf(fminf(best2, ob2), fmaxf(sec2, os2));
                if (ob2 > best2) { best2 = ob2; bi2 = oi2; }
            }
            const int bt1 = b * TT + t1;
            const int bt2 = b * TT + t2;
            pbest[ns * BB * TT + bt1] = best1;
            psec [ns * BB * TT + bt1] = sec1;
            pidx [ns * BB * TT + bt1] = ns * NPB + bi1;
            pbest[ns * BB * TT + bt2] = best2;
            psec [ns * BB * TT + bt2] = sec2;
            pidx [ns * BB * TT + bt2] = ns * NPB + bi2;
        }
    } else {
        // ---- single path: remainder targets 256..299 ----
        const int t = 256 + tl;
        float ax0 = 0.f, ay0 = 0.f, ax1 = 0.f, ay1 = 0.f;
        float aw = 0.f, ah = 0.f, aa = 0.f;
        if (t < TT)
            load_target(tgt, b * TT + t, ax0, ay0, ax1, ay1, aw, ah, aa);

        float best = -INFINITY, second = -INFINITY;
        int   bidxl = 0;
        #pragma unroll 9
        for (int k = 0; k < NPW; ++k) {
            const float4 q = sq[k0 + k];
            const float pw = q.z - q.x;
            const float ph = q.w - q.y;
            const float pa = pw * ph;
            giou_step(q, pa, pw, ph, ax0, ay0, ax1, ay1, aw, ah, aa, k,
                      best, second, bidxl);
        }
        int bidx = k0 + bidxl;

        rb1[tid] = best; rs1[tid] = second; ri1[tid] = bidx;
        __syncthreads();

        if (ng == 0 && t < TT) {
            for (int s = 1; s < 4; ++s) { // ascending wave = ascending n
                const float ob = rb1[s * 64 + tl];
                const float os = rs1[s * 64 + tl];
                const int   oi = ri1[s * 64 + tl];
                second = fmaxf(fminf(best, ob), fmaxf(second, os));
                if (ob > best) { best = ob; bidx = oi; }
            }
            const int bt = b * TT + t;
            pbest[ns * BB * TT + bt] = best;
            psec [ns * BB * TT + bt] = second;
            pidx [ns * BB * TT + bt] = ns * NPB + bidx;
        }
    }

    // ---- publish this split's results ----
    __syncthreads();                      // join wave0's global stores
    if (tid == 0) {
        __threadfence();                  // device-scope release (XCD L2s)
        atomicExch(&flags[blockIdx.x], MAGIC);
    }
    if (ns != 0) return;                  // block-uniform: siblings exit

    // ---- combiner: wait for 4 siblings (consecutive blockIdx) ----
    if (tid == 0) {
        const int fb = b * (3 * NSPLIT) + tc * NSPLIT;
        for (int s = 1; s < NSPLIT; ++s)
            while (atomicAdd(&flags[fb + s], 0) != MAGIC)
                __builtin_amdgcn_s_sleep(2);
        __threadfence();                  // device-scope acquire
    }
    __syncthreads();

    // ---- finish phase: combine splits for this (b,tc) chunk ----
    const int ntc = (tc < 2) ? 128 : 44;
    if (tid < ntc) {
        const int bt = b * TT + tc * 128 + tid;
        float best = -INFINITY, second = -INFINITY;
        int   bidx = 0;
        #pragma unroll
        for (int s = 0; s < NSPLIT; ++s) {    // ascending ns = ascending n
            const float ob = pbest[s * BB * TT + bt];
            const float os = psec [s * BB * TT + bt];
            const int   oi = pidx [s * BB * TT + bt];
            second = fmaxf(fminf(best, ob), fmaxf(second, os));
            if (ob > best) { best = ob; bidx = oi; }
        }

        if (best - second > MARGIN) {
            // approx argmax provably exact; recompute winner bit-exactly
            const float4 pb = pred[b * NN + bidx];
            const float4 tb = tgt[bt];
            const float g = giou_exact(pb, tb);
            const bool valid = (mask[bt] != 0) && (g >= 0.5f);
            out[bt]               = (float)bidx;
            out[BB * TT + bt]     = valid ? 1.f : 0.f;
            out[2 * BB * TT + bt] = g;
        } else {
            const int pos = atomicAdd(&scount, 1);
            sflag[pos] = tid;
        }
    }
    __syncthreads();

    // cooperative exact rescan of ambiguous targets: one wave per entry
    const int cnt  = scount;
    for (int f = ng; f < cnt; f += 4) {
        const int fbt = b * TT + tc * 128 + sflag[f];
        const float4 tb = tgt[fbt];

        float bestx = -INFINITY;
        int   bix   = NN;
        for (int n = tl; n < NN; n += 64) {   // ascending n per lane
            const float4 pb = pred[b * NN + n];
            const float g = giou_exact(pb, tb);
            if (g > bestx) { bestx = g; bix = n; }
        }
        // cross-lane reduce: max g, lowest n on bit-ties (numpy first-occ.)
        for (int off = 32; off >= 1; off >>= 1) {
            const float ob = __shfl_xor(bestx, off);
            const int   oi = __shfl_xor(bix, off);
            if (ob > bestx || (ob == bestx && oi < bix)) { bestx = ob; bix = oi; }
        }
        if (tl == 0) {
            const bool valid = (mask[fbt] != 0) && (bestx >= 0.5f);
            out[fbt]               = (float)bix;
            out[BB * TT + fbt]     = valid ? 1.f : 0.f;
            out[2 * BB * TT + fbt] = bestx;
        }
    }
}

extern "C" void kernel_launch(void* const* d_in, const int* in_sizes, int n_in,
                              void* d_out, int out_size, void* d_ws, size_t ws_size,
                              hipStream_t stream) {
    const float* pred = (const float*)d_in[0];
    const float* tgt  = (const float*)d_in[1];
    const unsigned char* mask = (const unsigned char*)d_in[2];
    float* out = (float*)d_out;

    const size_t seg = (size_t)NSPLIT * BB * TT * 4;   // 768 KB per array
    char* ws = (char*)d_ws;
    float* pbest = (float*)ws;
    float* psec  = (float*)(ws + seg);
    int*   pidx  = (int*)  (ws + 2 * seg);
    int*   flags = (int*)  (ws + 3 * seg);             // 1920 ints

    matcher_fused_kernel<<<dim3(BB * 3 * NSPLIT), dim3(256), 0, stream>>>(
        (const float4*)pred, (const float4*)tgt, mask,
        pbest, psec, pidx, flags, out);
}

// Round 6
// 99.948 us; speedup vs baseline: 1.3123x; 1.3123x over previous
//
#include <hip/hip_runtime.h>

// SimpleMatcher: B=128, N=900 preds, T=300 targets.
// out = [pred_idx (B*T), valid (B*T), max_iou (B*T)] as float.
//
// R11: R10's fused kernel finally yielded direct counters: 80.8us,
// VALUBusy 27.8%, Occupancy 27.7%, HBM 1.5%, conflicts 0. Diagnosis:
// (a) grid 1920 blocks @4/CU = 2 sequential scheduling batches (~2x),
// (b) spin-waiting combiners occupy slots, (c) global split round-trip.
// VALU floor is ~11us (34.56M GIoU / 64 lanes * ~26 inst * 2cyc / 1024
// SIMD). R11 rebuilds geometry: ONE dispatch, 640 blocks (single batch),
// block = (b, 64-target chunk), ALL 900 preds of b staged in LDS
// (14.4KB); the 4 waves split preds 4x225 for the SAME targets (one
// target/lane); cross-wave top-2 combine via 3KB LDS reduce -> final
// result IN-BLOCK. Wave0: MARGIN check + bit-exact winner recompute +
// store. Ambiguous targets: cooperative in-block exact rescan. No global
// intermediates, no flags/spin, no finish kernel.
// Numerics unchanged (R5..R10 all passed, absmax 1.0): min+max=sum
// identity, rcp GIoU, |approx-exact| <= ~4e-7 << MARGIN 2e-5, strict->
// first-occurrence argmax preserved (ascending k in wave, ascending wave
// ranges, strict > in combine), winner recomputed IEEE-exactly.
// Fixed floor: harness 256MiB ws-poison fill (~40us) stays in-window.

#define BB 128
#define NN 900
#define TT 300
#define TCHUNKS 5      // ceil(TT/64) target chunks per batch
#define WPB 4          // waves per block
#define PSPLIT 225     // preds per wave (NN / WPB)
#define MARGIN 2e-5f

// Bit-exact GIoU in numpy's exact expression order.
__device__ __forceinline__ float giou_exact(float4 pb, float4 tb) {
#pragma clang fp contract(off)
    float px0 = pb.x - 0.5f * pb.z, py0 = pb.y - 0.5f * pb.w;
    float px1 = pb.x + 0.5f * pb.z, py1 = pb.y + 0.5f * pb.w;
    float tx0 = tb.x - 0.5f * tb.z, ty0 = tb.y - 0.5f * tb.w;
    float tx1 = tb.x + 0.5f * tb.z, ty1 = tb.y + 0.5f * tb.w;
    float pa = (px1 - px0) * (py1 - py0);
    float ta = (tx1 - tx0) * (ty1 - ty0);
    float w  = fmaxf(fminf(px1, tx1) - fmaxf(px0, tx0), 0.f);
    float h  = fmaxf(fminf(py1, ty1) - fmaxf(py0, ty0), 0.f);
    float inter = w * h;
    float uni   = pa + ta - inter;
    float iou   = inter / uni;            // correctly-rounded IEEE div
    float ew = fmaxf(fmaxf(px1, tx1) - fminf(px0, tx0), 0.f);
    float eh = fmaxf(fmaxf(py1, ty1) - fminf(py0, ty0), 0.f);
    float ea = ew * eh;
    return iou - (ea - uni) / ea;         // correctly-rounded IEEE div
}

// Grid: BB * TCHUNKS = 640 blocks, 256 threads. Block owns (b, 64-target
// chunk); waves split the 900 preds 4 ways; lane owns one target.
__global__ __launch_bounds__(256, 4) void matcher_kernel(
    const float4* __restrict__ pred,      // [B*N] cxcywh
    const float4* __restrict__ tgt,       // [B*T] cxcywh
    const unsigned char* __restrict__ mask,
    float* __restrict__ out)
{
    __shared__ float4 sq[NN];             // all preds of b, xyxy (14.4 KB)
    __shared__ float rbv[256], rsv[256];  // cross-wave top-2 reduce
    __shared__ int   riv[256];
    __shared__ int   sflag[64];
    __shared__ int   scount;

    const int tc  = blockIdx.x % TCHUNKS;
    const int b   = blockIdx.x / TCHUNKS;
    const int tid = threadIdx.x;
    const int tl  = tid & 63;
    const int ng  = tid >> 6;

    if (tid == 0) scount = 0;

    // Stage + transform all 900 preds (4 coalesced rounds).
    for (int i = tid; i < NN; i += 256) {
        const float4 pb = pred[b * NN + i];
        float4 q;
        q.x = pb.x - 0.5f * pb.z;
        q.y = pb.y - 0.5f * pb.w;
        q.z = pb.x + 0.5f * pb.z;
        q.w = pb.y + 0.5f * pb.w;
        sq[i] = q;
    }
    __syncthreads();

    // Lane's target (dummy lanes compute but never store).
    const int  t      = tc * 64 + tl;
    const bool tvalid = (t < TT);
    const float4 tb = tgt[b * TT + (tvalid ? t : 0)];
    const float tx0 = tb.x - 0.5f * tb.z;
    const float ty0 = tb.y - 0.5f * tb.w;
    const float tx1 = tb.x + 0.5f * tb.z;
    const float ty1 = tb.y + 0.5f * tb.w;
    const float tw  = tx1 - tx0;
    const float th  = ty1 - ty0;
    const float ta  = tw * th;            // == reference area_t

    // Scan this wave's pred slice for this lane's target.
    const int k0 = ng * PSPLIT;
    float best = -INFINITY, second = -INFINITY;
    int   bidxl = 0;
    #pragma unroll 9
    for (int k = 0; k < PSPLIT; ++k) {
        const float4 q = sq[k0 + k];      // wave-uniform -> LDS broadcast
        const float pw = q.z - q.x;
        const float ph = q.w - q.y;
        const float pa = pw * ph;

        const float m1x = fminf(q.z, tx1);
        const float M0x = fmaxf(q.x, tx0);
        const float wr  = m1x - M0x;      // unclamped intersect width
        const float w   = fmaxf(wr, 0.f);
        const float m1y = fminf(q.w, ty1);
        const float M0y = fmaxf(q.y, ty0);
        const float hr  = m1y - M0y;
        const float h   = fmaxf(hr, 0.f);
        const float inter = w * h;
        const float uni   = (pa + ta) - inter;
        // min+max=sum identity: ew = max(px1,tx1)-min(px0,tx0) = pw+tw-wr
        const float ew = (pw + tw) - wr;
        const float eh = (ph + th) - hr;
        const float ea = ew * eh;
        // g = inter/uni - (ea-uni)/ea == (inter*ea + uni*(uni-ea))/(uni*ea)
        const float num = fmaf(inter, ea, uni * (uni - ea));
        const float g   = num * __builtin_amdgcn_rcpf(uni * ea);

        second = __builtin_amdgcn_fmed3f(g, best, second);  // new 2nd-max
        if (g > best) bidxl = k;
        best = fmaxf(best, g);
    }
    int bidx = k0 + bidxl;                // global pred index

    rbv[tid] = best; rsv[tid] = second; riv[tid] = bidx;
    __syncthreads();

    if (ng == 0) {
        // Combine the 4 wave slices (ascending wave = ascending n).
        for (int s = 1; s < WPB; ++s) {
            const float ob = rbv[s * 64 + tl];
            const float os = rsv[s * 64 + tl];
            const int   oi = riv[s * 64 + tl];
            second = fmaxf(fminf(best, ob), fmaxf(second, os));
            if (ob > best) { best = ob; bidx = oi; }
        }

        if (tvalid) {
            const int bt = b * TT + t;
            if (best - second > MARGIN) {
                // approx argmax provably exact; recompute winner exactly
                const float4 pb = pred[b * NN + bidx];
                const float4 tbr = tgt[bt];
                const float g = giou_exact(pb, tbr);
                const bool valid = (mask[bt] != 0) && (g >= 0.5f);
                out[bt]               = (float)bidx;
                out[BB * TT + bt]     = valid ? 1.f : 0.f;
                out[2 * BB * TT + bt] = g;
            } else {
                const int pos = atomicAdd(&scount, 1);
                sflag[pos] = tl;
            }
        }
    }
    __syncthreads();

    // Cooperative exact rescan of ambiguous targets: one wave per entry.
    const int cnt = scount;
    for (int f = ng; f < cnt; f += WPB) {
        const int fbt = b * TT + tc * 64 + sflag[f];
        const float4 tbr = tgt[fbt];

        float bestx = -INFINITY;
        int   bix   = NN;
        for (int n = tl; n < NN; n += 64) {   // ascending n per lane
            const float4 pb = pred[b * NN + n];
            const float g = giou_exact(pb, tbr);
            if (g > bestx) { bestx = g; bix = n; }
        }
        // cross-lane reduce: max g, lowest n on bit-ties (numpy first-occ.)
        for (int off = 32; off >= 1; off >>= 1) {
            const float ob = __shfl_xor(bestx, off);
            const int   oi = __shfl_xor(bix, off);
            if (ob > bestx || (ob == bestx && oi < bix)) { bestx = ob; bix = oi; }
        }
        if (tl == 0) {
            const bool valid = (mask[fbt] != 0) && (bestx >= 0.5f);
            out[fbt]               = (float)bix;
            out[BB * TT + fbt]     = valid ? 1.f : 0.f;
            out[2 * BB * TT + fbt] = bestx;
        }
    }
}

extern "C" void kernel_launch(void* const* d_in, const int* in_sizes, int n_in,
                              void* d_out, int out_size, void* d_ws, size_t ws_size,
                              hipStream_t stream) {
    const float* pred = (const float*)d_in[0];
    const float* tgt  = (const float*)d_in[1];
    const unsigned char* mask = (const unsigned char*)d_in[2];
    float* out = (float*)d_out;

    matcher_kernel<<<dim3(BB * TCHUNKS), dim3(256), 0, stream>>>(
        (const float4*)pred, (const float4*)tgt, mask, out);
}

// Round 7
// 97.560 us; speedup vs baseline: 1.3445x; 1.0245x over previous
//
#include <hip/hip_runtime.h>

// SimpleMatcher: B=128, N=900 preds, T=300 targets.
// out = [pred_idx (B*T), valid (B*T), max_iou (B*T)] as float.
//
// R12: R11's counters: kernel 48.6us, VALUBusy 57%, Occupancy 16% (!).
// Grid 640 x 4 waves = ~1.25 waves/SIMD -- LDS latency + combine/rescan
// tails are exposed, not hidden. VALU-busy absolute time = 27.7us = the
// instruction-stream floor. Fix occupancy first: 512-thread blocks
// (8 waves), preds split 4x113 + 4x112 (wave base = ng*112 + min(ng,4);
// no dummy preds; ascending-n order across waves preserved -> numpy
// first-occurrence argmax semantics intact). Grid stays 640 = single
// scheduling batch; ~20 waves/CU = ~5/SIMD hides LDS latency.
// Everything else identical to R11 (passed, absmax 1.0): all-preds-in-LDS
// (14.4KB), in-block top-2 combine, MARGIN 2e-5 + bit-exact winner
// recompute, cooperative exact rescan for ambiguous targets.
// Fixed floor: harness 256MiB ws-poison fill (~40us) stays in-window.

#define BB 128
#define NN 900
#define TT 300
#define TCHUNKS 5      // ceil(TT/64) target chunks per batch
#define WPB 8          // waves per block
#define MARGIN 2e-5f

// Bit-exact GIoU in numpy's exact expression order.
__device__ __forceinline__ float giou_exact(float4 pb, float4 tb) {
#pragma clang fp contract(off)
    float px0 = pb.x - 0.5f * pb.z, py0 = pb.y - 0.5f * pb.w;
    float px1 = pb.x + 0.5f * pb.z, py1 = pb.y + 0.5f * pb.w;
    float tx0 = tb.x - 0.5f * tb.z, ty0 = tb.y - 0.5f * tb.w;
    float tx1 = tb.x + 0.5f * tb.z, ty1 = tb.y + 0.5f * tb.w;
    float pa = (px1 - px0) * (py1 - py0);
    float ta = (tx1 - tx0) * (ty1 - ty0);
    float w  = fmaxf(fminf(px1, tx1) - fmaxf(px0, tx0), 0.f);
    float h  = fmaxf(fminf(py1, ty1) - fmaxf(py0, ty0), 0.f);
    float inter = w * h;
    float uni   = pa + ta - inter;
    float iou   = inter / uni;            // correctly-rounded IEEE div
    float ew = fmaxf(fmaxf(px1, tx1) - fminf(px0, tx0), 0.f);
    float eh = fmaxf(fmaxf(py1, ty1) - fminf(py0, ty0), 0.f);
    float ea = ew * eh;
    return iou - (ea - uni) / ea;         // correctly-rounded IEEE div
}

// One GIoU step vs the LDS-broadcast pred q (pa,pw,ph derived), top-2.
__device__ __forceinline__ void giou_step(
    const float4 q,
    const float tx0, const float ty0, const float tx1, const float ty1,
    const float tw, const float th, const float ta, const int k,
    float& best, float& second, int& bidxl)
{
    const float pw = q.z - q.x;
    const float ph = q.w - q.y;
    const float pa = pw * ph;

    const float m1x = fminf(q.z, tx1);
    const float M0x = fmaxf(q.x, tx0);
    const float wr  = m1x - M0x;          // unclamped intersect width
    const float w   = fmaxf(wr, 0.f);
    const float m1y = fminf(q.w, ty1);
    const float M0y = fmaxf(q.y, ty0);
    const float hr  = m1y - M0y;
    const float h   = fmaxf(hr, 0.f);
    const float inter = w * h;
    const float uni   = (pa + ta) - inter;
    // min+max=sum identity: ew = max(px1,tx1)-min(px0,tx0) = pw+tw-wr
    const float ew = (pw + tw) - wr;
    const float eh = (ph + th) - hr;
    const float ea = ew * eh;
    // g = inter/uni - (ea-uni)/ea == (inter*ea + uni*(uni-ea))/(uni*ea)
    const float num = fmaf(inter, ea, uni * (uni - ea));
    const float g   = num * __builtin_amdgcn_rcpf(uni * ea);

    second = __builtin_amdgcn_fmed3f(g, best, second);  // new 2nd-max
    if (g > best) bidxl = k;
    best = fmaxf(best, g);
}

// Grid: BB * TCHUNKS = 640 blocks, 512 threads (8 waves). Block owns
// (b, 64-target chunk); waves split the 900 preds 4x113 + 4x112; lane
// owns one target.
__global__ __launch_bounds__(512, 4) void matcher_kernel(
    const float4* __restrict__ pred,      // [B*N] cxcywh
    const float4* __restrict__ tgt,       // [B*T] cxcywh
    const unsigned char* __restrict__ mask,
    float* __restrict__ out)
{
    __shared__ float4 sq[NN];             // all preds of b, xyxy (14.4 KB)
    __shared__ float rbv[512], rsv[512];  // cross-wave top-2 reduce (6 KB)
    __shared__ int   riv[512];
    __shared__ int   sflag[64];
    __shared__ int   scount;

    const int tc  = blockIdx.x % TCHUNKS;
    const int b   = blockIdx.x / TCHUNKS;
    const int tid = threadIdx.x;
    const int tl  = tid & 63;
    const int ng  = tid >> 6;

    if (tid == 0) scount = 0;

    // Stage + transform all 900 preds (2 coalesced rounds).
    for (int i = tid; i < NN; i += 512) {
        const float4 pb = pred[b * NN + i];
        float4 q;
        q.x = pb.x - 0.5f * pb.z;
        q.y = pb.y - 0.5f * pb.w;
        q.z = pb.x + 0.5f * pb.z;
        q.w = pb.y + 0.5f * pb.w;
        sq[i] = q;
    }
    __syncthreads();

    // Lane's target (dummy lanes compute but never store).
    const int  t      = tc * 64 + tl;
    const bool tvalid = (t < TT);
    const float4 tb = tgt[b * TT + (tvalid ? t : 0)];
    const float tx0 = tb.x - 0.5f * tb.z;
    const float ty0 = tb.y - 0.5f * tb.w;
    const float tx1 = tb.x + 0.5f * tb.z;
    const float ty1 = tb.y + 0.5f * tb.w;
    const float tw  = tx1 - tx0;
    const float th  = ty1 - ty0;
    const float ta  = tw * th;            // == reference area_t

    // Scan this wave's pred slice: waves 0..3 get 113, waves 4..7 get 112.
    const int k0 = ng * 112 + min(ng, 4);
    float best = -INFINITY, second = -INFINITY;
    int   bidxl = 0;
    #pragma unroll 8
    for (int k = 0; k < 112; ++k) {
        const float4 q = sq[k0 + k];      // wave-uniform -> LDS broadcast
        giou_step(q, tx0, ty0, tx1, ty1, tw, th, ta, k, best, second, bidxl);
    }
    if (ng < 4) {                         // wave-uniform tail iteration
        const float4 q = sq[k0 + 112];
        giou_step(q, tx0, ty0, tx1, ty1, tw, th, ta, 112, best, second, bidxl);
    }
    int bidx = k0 + bidxl;                // global pred index

    rbv[tid] = best; rsv[tid] = second; riv[tid] = bidx;
    __syncthreads();

    if (ng == 0) {
        // Combine the 8 wave slices (ascending wave = ascending n).
        for (int s = 1; s < WPB; ++s) {
            const float ob = rbv[s * 64 + tl];
            const float os = rsv[s * 64 + tl];
            const int   oi = riv[s * 64 + tl];
            second = fmaxf(fminf(best, ob), fmaxf(second, os));
            if (ob > best) { best = ob; bidx = oi; }
        }

        if (tvalid) {
            const int bt = b * TT + t;
            if (best - second > MARGIN) {
                // approx argmax provably exact; recompute winner exactly
                const float4 pb = pred[b * NN + bidx];
                const float4 tbr = tgt[bt];
                const float g = giou_exact(pb, tbr);
                const bool valid = (mask[bt] != 0) && (g >= 0.5f);
                out[bt]               = (float)bidx;
                out[BB * TT + bt]     = valid ? 1.f : 0.f;
                out[2 * BB * TT + bt] = g;
            } else {
                const int pos = atomicAdd(&scount, 1);
                sflag[pos] = tl;
            }
        }
    }
    __syncthreads();

    // Cooperative exact rescan of ambiguous targets: one wave per entry.
    const int cnt = scount;
    for (int f = ng; f < cnt; f += WPB) {
        const int fbt = b * TT + tc * 64 + sflag[f];
        const float4 tbr = tgt[fbt];

        float bestx = -INFINITY;
        int   bix   = NN;
        for (int n = tl; n < NN; n += 64) {   // ascending n per lane
            const float4 pb = pred[b * NN + n];
            const float g = giou_exact(pb, tbr);
            if (g > bestx) { bestx = g; bix = n; }
        }
        // cross-lane reduce: max g, lowest n on bit-ties (numpy first-occ.)
        for (int off = 32; off >= 1; off >>= 1) {
            const float ob = __shfl_xor(bestx, off);
            const int   oi = __shfl_xor(bix, off);
            if (ob > bestx || (ob == bestx && oi < bix)) { bestx = ob; bix = oi; }
        }
        if (tl == 0) {
            const bool valid = (mask[fbt] != 0) && (bestx >= 0.5f);
            out[fbt]               = (float)bix;
            out[BB * TT + fbt]     = valid ? 1.f : 0.f;
            out[2 * BB * TT + fbt] = bestx;
        }
    }
}

extern "C" void kernel_launch(void* const* d_in, const int* in_sizes, int n_in,
                              void* d_out, int out_size, void* d_ws, size_t ws_size,
                              hipStream_t stream) {
    const float* pred = (const float*)d_in[0];
    const float* tgt  = (const float*)d_in[1];
    const unsigned char* mask = (const unsigned char*)d_in[2];
    float* out = (float*)d_out;

    matcher_kernel<<<dim3(BB * TCHUNKS), dim3(512), 0, stream>>>(
        (const float4*)pred, (const float4*)tgt, mask, out);
}